// Round 4
// baseline (398.241 us; speedup 1.0000x reference)
//
#include <hip/hip_runtime.h>

#define NB 128
#define NLQ 256   // sequence length L
#define ND 512    // feature dim D
#define NLAYERS 6
#define DD (ND*ND)
#define MN (1024*ND)
#define HTB 131072   // floats per batch in h0T: 512*256

typedef short bf16x8 __attribute__((ext_vector_type(8)));
typedef float f32x4 __attribute__((ext_vector_type(4)));
typedef unsigned int u32x2 __attribute__((ext_vector_type(2)));

__device__ __forceinline__ float wave_max(float v){
  #pragma unroll
  for(int off=32; off; off>>=1) v = fmaxf(v, __shfl_xor(v, off));
  return v;
}
__device__ __forceinline__ float wave_sum(float v){
  #pragma unroll
  for(int off=32; off; off>>=1) v += __shfl_xor(v, off);
  return v;
}

// split two fp32 into packed bf16 hi-plane word and lo-plane word
__device__ __forceinline__ void split2(float x0, float x1, unsigned int& hi, unsigned int& lo){
  unsigned int u0 = __float_as_uint(x0), u1 = __float_as_uint(x1);
  unsigned int h0 = u0 & 0xFFFF0000u, h1 = u1 & 0xFFFF0000u;
  hi = (u0 >> 16) | h1;
  float d0 = x0 - __uint_as_float(h0);
  float d1 = x1 - __uint_as_float(h1);
  lo = (__float_as_uint(d0) >> 16) | (__float_as_uint(d1) & 0xFFFF0000u);
}

__global__ __launch_bounds__(256) void k_scal(const float* __restrict__ a_stack,
                                              float* __restrict__ scal){
  int layer = blockIdx.x;
  const float* a = a_stack + (size_t)layer*2*ND;
  int t = threadIdx.x;
  float v0 = a[t];
  float v1 = a[256 + t];
  v0 = wave_sum(v0); v1 = wave_sum(v1);
  __shared__ float s0[4], s1[4];
  int wave = t>>6, lane = t&63;
  if(lane==0){ s0[wave]=v0; s1[wave]=v1; }
  __syncthreads();
  if(t==0){
    scal[layer*2+0] = s0[0]+s0[1]+s0[2]+s0[3];
    scal[layer*2+1] = s1[0]+s1[1]+s1[2]+s1[3];
  }
}

// v_l[i] = dot(W_{l+1}[i,:], a2_{l+1})
__global__ __launch_bounds__(256) void k_wa2(const float* __restrict__ Wst,
                                             const float* __restrict__ ast,
                                             float* __restrict__ v){
  int l  = blockIdx.x >> 7;
  int rg = blockIdx.x & 127;
  int i  = rg*4 + (threadIdx.x>>6);
  int lane = threadIdx.x & 63;
  const float4* wr = (const float4*)(Wst + (size_t)(l+1)*DD + (size_t)i*ND);
  const float4* ar = (const float4*)(ast + (size_t)(l+1)*2*ND + ND);
  float4 w0=wr[lane], w1=wr[lane+64], a0=ar[lane], a1=ar[lane+64];
  float d = w0.x*a0.x + w0.y*a0.y + w0.z*a0.z + w0.w*a0.w
          + w1.x*a1.x + w1.y*a1.y + w1.z*a1.z + w1.w*a1.w;
  d = wave_sum(d);
  if(lane==0) v[l*ND + i] = d;
}

// pack adj transposed into bitmasks: adjT[b][j][ic] bit r = adj[b][ic*64+r][j]
__global__ __launch_bounds__(256) void k_adjp(const int* __restrict__ adj,
                                              unsigned long long* __restrict__ adjT){
  __shared__ unsigned char tile[64][260];
  int b  = blockIdx.x >> 2;
  int ic = blockIdx.x & 3;
  int i0 = ic*64;
  int t = threadIdx.x;
  for(int r = 0; r < 64; r++)
    tile[r][t] = (unsigned char)(adj[((size_t)b*NLQ + i0 + r)*NLQ + t] > 0);
  __syncthreads();
  unsigned long long m = 0;
  #pragma unroll
  for(int r = 0; r < 64; r++)
    m |= ((unsigned long long)tile[r][t]) << r;
  adjT[((size_t)b*NLQ + t)*4 + ic] = m;
}

__global__ __launch_bounds__(256) void k_posw(const float* __restrict__ x, float* __restrict__ xp,
    const int* __restrict__ left, const int* __restrict__ asp, const int* __restrict__ tl){
  int idx = blockIdx.x*256 + threadIdx.x;
  int b   = idx >> 15;
  int rem = idx & 32767;
  int j   = rem >> 7;
  float l = (float)left[b];
  float aspf = (float)asp[b];
  float r = l + aspf - 1.f;
  float tlf = (float)tl[b];
  float ctx = tlf - aspf;
  float jf = (float)j;
  float w;
  if(jf < l)        w = 1.f - (l - jf)/ctx;
  else if(jf <= r)  w = 0.f;
  else if(jf < tlf) w = 1.f - (jf - r)/ctx;
  else              w = 0.f;
  float4 v = ((const float4*)x)[idx];
  v.x *= w; v.y *= w; v.z *= w; v.w *= w;
  ((float4*)xp)[idx] = v;
}

// ---- split-bf16 MFMA GEMM tile: C[128x128] = A[128x512]@W[512x128] ----
// TRANS=0: C row-major [M][512]. TRANS=1: C = h0T layout [b][d][i] (transposed via LDS bounce).
#define ROWB 80
template<int TRANS>
__device__ __forceinline__ void gemm_tile(const float* __restrict__ A,
                                          const float* __restrict__ W,
                                          float* __restrict__ C,
                                          int mtile, int ntile, unsigned char* lds){
  unsigned char* Ahi = lds;
  unsigned char* Alo = lds + 128*ROWB;
  unsigned char* Bhi = lds + 2*128*ROWB;
  unsigned char* Blo = lds + 3*128*ROWB;

  int t = threadIdx.x;
  int m0 = mtile*128, n0 = ntile*128;
  int lane = t & 63, wid = t >> 6;
  int wr = wid >> 1, wc = wid & 1;
  int lrow = lane & 15, kb = lane >> 4;

  f32x4 acc[4][4];
  #pragma unroll
  for(int mi=0;mi<4;mi++)
    #pragma unroll
    for(int ni=0;ni<4;ni++)
      acc[mi][ni] = (f32x4){0.f,0.f,0.f,0.f};

  int a_row = t >> 3;
  int a_kq  = t & 7;
  int w_n   = t & 127;
  int w_half= t >> 7;

  float4 pa[4];
  float  pw[16];

  #pragma unroll
  for(int p=0;p<4;p++)
    pa[p] = *(const float4*)(A + (size_t)(m0 + a_row + p*32)*ND + a_kq*4);
  #pragma unroll
  for(int q=0;q<4;q++){
    const float* wp = W + (size_t)(w_half*16 + q*4)*ND + n0 + w_n;
    pw[q*4+0]=wp[0]; pw[q*4+1]=wp[ND]; pw[q*4+2]=wp[2*ND]; pw[q*4+3]=wp[3*ND];
  }

  for(int k0=0; k0<ND; k0+=32){
    #pragma unroll
    for(int p=0;p<4;p++){
      int row = a_row + p*32;
      unsigned int h01, l01, h23, l23;
      split2(pa[p].x, pa[p].y, h01, l01);
      split2(pa[p].z, pa[p].w, h23, l23);
      int off = row*ROWB + a_kq*8;
      *(u32x2*)(Ahi + off) = (u32x2){h01, h23};
      *(u32x2*)(Alo + off) = (u32x2){l01, l23};
    }
    #pragma unroll
    for(int q=0;q<4;q++){
      unsigned int h01, l01, h23, l23;
      split2(pw[q*4+0], pw[q*4+1], h01, l01);
      split2(pw[q*4+2], pw[q*4+3], h23, l23);
      int off = w_n*ROWB + (w_half*4 + q)*8;
      *(u32x2*)(Bhi + off) = (u32x2){h01, h23};
      *(u32x2*)(Blo + off) = (u32x2){l01, l23};
    }
    __syncthreads();

    if(k0 + 32 < ND){
      int kn = k0 + 32;
      #pragma unroll
      for(int p=0;p<4;p++)
        pa[p] = *(const float4*)(A + (size_t)(m0 + a_row + p*32)*ND + kn + a_kq*4);
      #pragma unroll
      for(int q=0;q<4;q++){
        const float* wp = W + (size_t)(kn + w_half*16 + q*4)*ND + n0 + w_n;
        pw[q*4+0]=wp[0]; pw[q*4+1]=wp[ND]; pw[q*4+2]=wp[2*ND]; pw[q*4+3]=wp[3*ND];
      }
    }

    bf16x8 ah[4], al[4], bh[4], bl[4];
    #pragma unroll
    for(int mi=0;mi<4;mi++){
      int r = wr*64 + mi*16 + lrow;
      int off = r*ROWB + kb*16;
      ah[mi] = *(const bf16x8*)(Ahi + off);
      al[mi] = *(const bf16x8*)(Alo + off);
    }
    #pragma unroll
    for(int ni=0;ni<4;ni++){
      int n = wc*64 + ni*16 + lrow;
      int off = n*ROWB + kb*16;
      bh[ni] = *(const bf16x8*)(Bhi + off);
      bl[ni] = *(const bf16x8*)(Blo + off);
    }

    #pragma unroll
    for(int mi=0;mi<4;mi++)
      #pragma unroll
      for(int ni=0;ni<4;ni++){
        acc[mi][ni] = __builtin_amdgcn_mfma_f32_16x16x32_bf16(ah[mi], bh[ni], acc[mi][ni], 0,0,0);
        acc[mi][ni] = __builtin_amdgcn_mfma_f32_16x16x32_bf16(ah[mi], bl[ni], acc[mi][ni], 0,0,0);
        acc[mi][ni] = __builtin_amdgcn_mfma_f32_16x16x32_bf16(al[mi], bh[ni], acc[mi][ni], 0,0,0);
      }
    __syncthreads();
  }

  int rg = lane >> 4;
  int cc = lane & 15;
  if(TRANS == 0){
    #pragma unroll
    for(int mi=0;mi<4;mi++)
      #pragma unroll
      for(int ni=0;ni<4;ni++){
        int col = n0 + wc*64 + ni*16 + cc;
        #pragma unroll
        for(int q=0;q<4;q++){
          int row = m0 + wr*64 + mi*16 + rg*4 + q;
          C[(size_t)row*ND + col] = acc[mi][ni][q];
        }
      }
  } else {
    // transpose 128x128 tile via LDS in two 64-col passes -> h0T[b][d][i]
    float* CT = (float*)lds;   // 64*130 floats = 33280 B (fits in staging LDS)
    int b = m0 >> 8;
    int ibase = m0 & 255;
    #pragma unroll
    for(int p=0;p<2;p++){
      if(wc == p){
        #pragma unroll
        for(int mi=0;mi<4;mi++)
          #pragma unroll
          for(int ni=0;ni<4;ni++)
            #pragma unroll
            for(int q=0;q<4;q++)
              CT[(ni*16+cc)*130 + wr*64 + mi*16 + rg*4 + q] = acc[mi][ni][q];
      }
      __syncthreads();
      int lcol = t >> 6;
      int lrow2 = (t & 63)*2;
      #pragma unroll
      for(int u=0;u<16;u++){
        int c = lcol + u*4;
        float2 v2 = *(float2*)&CT[c*130 + lrow2];
        *(float2*)&C[(size_t)b*HTB + (size_t)(n0 + p*64 + c)*256 + ibase + lrow2] = v2;
      }
      __syncthreads();
    }
  }
}

__global__ __launch_bounds__(256) void k_gemm_t(const float* __restrict__ A,
                                                const float* __restrict__ W,
                                                float* __restrict__ C){
  __shared__ unsigned char lds[4*128*ROWB];
  gemm_tile<1>(A, W, C, blockIdx.x>>2, blockIdx.x&3, lds);
}

__global__ __launch_bounds__(256) void k_gemm_b(const float* __restrict__ Abase, long aStride,
                                                const float* __restrict__ Wbase,
                                                float* __restrict__ Cbase){
  __shared__ unsigned char lds[4*128*ROWB];
  int l  = blockIdx.x >> 5;
  int tb = blockIdx.x & 31;
  gemm_tile<0>(Abase + (size_t)l*aStride, Wbase + (size_t)(l+1)*DD,
               Cbase + (size_t)l*MN, tb>>2, tb&3, lds);
}

// t-partials from h0T: tp[half][b][j] = sum_{d in half} h0T[b][d][j]*a2[d]
__global__ __launch_bounds__(256) void k_tT(const float* __restrict__ hT,
                                            const float* __restrict__ a2,
                                            float* __restrict__ tp){
  int bid = blockIdx.x;
  int b = bid & 127, half = bid >> 7;
  int j = threadIdx.x;
  const float* p = hT + (size_t)b*HTB + (size_t)half*256*256 + j;
  float s = 0.f;
  #pragma unroll 8
  for(int d=0; d<256; d++) s = fmaf(p[d*256], a2[half*256 + d], s);
  tp[half*32768 + b*256 + j] = s;
}

// layer-0 attention, MFMA aggregation. i-tile=32; 8 blocks per batch (same XCD).
#define ATTROW 528
__global__ __launch_bounds__(256) void k_attn0(
    const float* __restrict__ hT, const unsigned long long* __restrict__ adjT,
    const float* __restrict__ tpart, const float* __restrict__ scal,
    const int* __restrict__ left, const int* __restrict__ asp, const int* __restrict__ tl,
    float* __restrict__ h1){
  __shared__ unsigned char attP[2*32*ATTROW];   // 33792: bf16 hi, lo planes [32 i][256 j]
  __shared__ unsigned char Bs[2*256*80];        // 40960: B-tile [256 d][32 j] hi/lo
  __shared__ float red[2][4][32];
  unsigned char* attH = attP;
  unsigned char* attL = attP + 32*ATTROW;
  unsigned char* BsH = Bs;
  unsigned char* BsL = Bs + 256*80;

  int bid = blockIdx.x;
  int b  = bid & 127;      // same-b blocks land on same XCD (bid mod 8 == b mod 8)
  int ic = bid >> 7;
  int i0 = ic*32;
  int tid = threadIdx.x;
  int lane = tid & 63, w = tid >> 6;
  int il = lane & 31;
  int jh = lane >> 5;
  int i  = i0 + il;
  float S0 = scal[0], S1 = scal[1];
  const float* hTb = hT + (size_t)b*HTB;

  // ---- phase 1: scores + softmax, lanes = i ----
  float e[32];
  unsigned int bits = 0;
  float m = -3.0e38f;
  int jbase = w*64 + jh*32;
  int iw = i >> 6;
  #pragma unroll
  for(int jj=0; jj<32; jj++){
    int j = jbase + jj;
    float v0 = hTb[(size_t)(2*j)*256 + i];
    float v1 = hTb[(size_t)(2*j+1)*256 + i];
    float tj = tpart[b*256 + j] + tpart[32768 + b*256 + j];
    unsigned long long word = adjT[((size_t)b*NLQ + j)*4 + iw];
    int bit = (int)((word >> (i & 63)) & 1ull);
    float ev = fmaxf(fmaf(S0, v0, fmaf(S1, v1, tj)), 0.f);
    e[jj] = ev;
    bits |= ((unsigned int)bit) << jj;
    if(bit) m = fmaxf(m, ev);
  }
  m = fmaxf(m, __shfl_xor(m, 32));
  red[0][w][il] = m;
  __syncthreads();
  m = fmaxf(fmaxf(red[0][0][il], red[0][1][il]), fmaxf(red[0][2][il], red[0][3][il]));
  float s = 0.f;
  #pragma unroll
  for(int jj=0; jj<32; jj++){
    float p = ((bits>>jj)&1) ? __expf(e[jj]-m) : 0.f;
    e[jj] = p;
    s += p;
  }
  s += __shfl_xor(s, 32);
  red[1][w][il] = s;
  __syncthreads();
  s = red[1][0][il]+red[1][1][il]+red[1][2][il]+red[1][3][il];
  float inv = 1.f/s;
  #pragma unroll
  for(int jj=0; jj<32; jj+=2){
    unsigned int hi, lo;
    split2(e[jj]*inv, e[jj+1]*inv, hi, lo);
    int off = il*ATTROW + (jbase + jj)*2;
    *(unsigned int*)(attH + off) = hi;
    *(unsigned int*)(attL + off) = lo;
  }

  // ---- phase 2: O[i][d] = att @ h via MFMA (A=att[32x256], B=h0T[d][j]) ----
  int wm = w >> 1, wn = w & 1;
  int lrow = lane & 15, kb = lane >> 4;
  float lf=(float)left[b], aspf=(float)asp[b], tlf=(float)tl[b];
  float rr=lf+aspf-1.f, ctx=tlf-aspf;
  int rg = lane >> 4, cc = lane & 15;

  for(int dp=0; dp<2; dp++){
    int d0 = dp*256;
    f32x4 acc[8];
    #pragma unroll
    for(int ni=0;ni<8;ni++) acc[ni] = (f32x4){0.f,0.f,0.f,0.f};
    for(int ks=0; ks<8; ks++){
      int j0 = ks*32;
      __syncthreads();
      const float* src = hTb + (size_t)(d0 + tid)*256 + j0;
      #pragma unroll
      for(int q4=0; q4<8; q4++){
        float4 v = *(const float4*)(src + q4*4);
        unsigned int h01,l01,h23,l23;
        split2(v.x,v.y,h01,l01);
        split2(v.z,v.w,h23,l23);
        int off = tid*80 + q4*8;
        *(u32x2*)(BsH + off) = (u32x2){h01,h23};
        *(u32x2*)(BsL + off) = (u32x2){l01,l23};
      }
      __syncthreads();
      bf16x8 ah, al;
      {
        int off = (wm*16 + lrow)*ATTROW + j0*2 + kb*16;
        ah = *(const bf16x8*)(attH + off);
        al = *(const bf16x8*)(attL + off);
      }
      #pragma unroll
      for(int ni=0; ni<8; ni++){
        int off = (wn*128 + ni*16 + lrow)*80 + kb*16;
        bf16x8 bh = *(const bf16x8*)(BsH + off);
        bf16x8 bl = *(const bf16x8*)(BsL + off);
        acc[ni] = __builtin_amdgcn_mfma_f32_16x16x32_bf16(ah, bh, acc[ni], 0,0,0);
        acc[ni] = __builtin_amdgcn_mfma_f32_16x16x32_bf16(ah, bl, acc[ni], 0,0,0);
        acc[ni] = __builtin_amdgcn_mfma_f32_16x16x32_bf16(al, bh, acc[ni], 0,0,0);
      }
    }
    #pragma unroll
    for(int q=0;q<4;q++){
      int row = i0 + wm*16 + rg*4 + q;
      float fi = (float)row;
      float wgt;
      if(fi < lf)       wgt = 1.f-(lf-fi)/ctx;
      else if(fi <= rr) wgt = 0.f;
      else if(fi < tlf) wgt = 1.f-(fi-rr)/ctx;
      else              wgt = 0.f;
      #pragma unroll
      for(int ni=0;ni<8;ni++){
        int col = d0 + wn*128 + ni*16 + cc;
        h1[((size_t)b*NLQ + row)*ND + col] = wgt*fmaxf(acc[ni][q], 0.f);
      }
    }
  }
}

// T[l][b*256+j] = h1[b,j,:] . v_l
__global__ __launch_bounds__(256) void k_tv(const float* __restrict__ h1,
                                            const float* __restrict__ v,
                                            float* __restrict__ T){
  int row  = blockIdx.x*4 + (threadIdx.x>>6);
  int lane = threadIdx.x & 63;
  const float4* hr = (const float4*)(h1 + (size_t)row*ND);
  float4 h0 = hr[lane], h1v = hr[lane+64];
  float s0,s1,s2,s3,s4;
  #define DOTV(SL, L) { \
    const float4* vr = (const float4*)(v + (L)*ND); \
    float4 v0 = vr[lane], v1 = vr[lane+64]; \
    float dd = h0.x*v0.x+h0.y*v0.y+h0.z*v0.z+h0.w*v0.w \
             + h1v.x*v1.x+h1v.y*v1.y+h1v.z*v1.z+h1v.w*v1.w; \
    SL = wave_sum(dd); }
  DOTV(s0,0) DOTV(s1,1) DOTV(s2,2) DOTV(s3,3) DOTV(s4,4)
  #undef DOTV
  if(lane==0){
    T[0*32768 + row]=s0; T[1*32768 + row]=s1; T[2*32768 + row]=s2;
    T[3*32768 + row]=s3; T[4*32768 + row]=s4;
  }
}

__global__ __launch_bounds__(256) void k_rows(const float* __restrict__ h1,
                                              const int* __restrict__ left, const int* __restrict__ asp,
                                              float* __restrict__ R){
  int b = blockIdx.x;
  int nk = asp[b], l0 = left[b];
  const float4* src = (const float4*)(h1 + (size_t)b*NLQ*ND);
  float4* dst = (float4*)(R + (size_t)b*8*ND);
  #pragma unroll
  for(int u=0; u<4; u++){
    int f4 = threadIdx.x + u*256;
    int k = f4 >> 7, c = f4 & 127;
    float4 val = (k<nk) ? src[(size_t)(l0+k)*128 + c] : (float4){0.f,0.f,0.f,0.f};
    dst[f4] = val;
  }
}

// all 25 (layer,row) atts for one batch; y = att @ h1. 2 blocks per b (d halves).
__global__ __launch_bounds__(256) void k_att5(const float* __restrict__ h1,
    const float* __restrict__ Hasp, const float* __restrict__ T,
    const int* __restrict__ adj, const float* __restrict__ scal,
    const int* __restrict__ left, const int* __restrict__ asp,
    float* __restrict__ y){
  __shared__ float att[25][260];
  int b  = blockIdx.x & 127;   // same-b pair on same XCD
  int dh = blockIdx.x >> 7;
  int tid = threadIdx.x, lane = tid&63, w = tid>>6;
  int nk = asp[b], l0 = left[b];

  for(int r = w; r < 25; r += 4){
    int l = r/5, k = r - l*5;
    if(k < nk){
      float S0 = scal[2*(l+1)], S1 = scal[2*(l+1)+1];
      const float2* hrow = (const float2*)(Hasp + (size_t)l*MN + (size_t)(b*8+k)*ND);
      const int* arow = adj + ((size_t)b*NLQ + (l0+k))*NLQ;
      const float* Tl = T + l*32768 + b*256;
      float e[4]; int av[4];
      float m = -3.0e38f;
      #pragma unroll
      for(int q=0;q<4;q++){
        int j = lane + 64*q;
        float2 hp = hrow[j];
        av[q] = arow[j];
        e[q] = fmaxf(S0*hp.x + S1*hp.y + Tl[j], 0.f);
        if(av[q] > 0) m = fmaxf(m, e[q]);
      }
      m = wave_max(m);
      float pp[4]; float s = 0.f;
      #pragma unroll
      for(int q=0;q<4;q++){
        pp[q] = (av[q] > 0) ? __expf(e[q]-m) : 0.f;
        s += pp[q];
      }
      s = wave_sum(s);
      float inv = 1.f/s;
      #pragma unroll
      for(int q=0;q<4;q++) att[r][lane+64*q] = pp[q]*inv;
    } else {
      #pragma unroll
      for(int q=0;q<4;q++) att[r][lane+64*q] = 0.f;
    }
  }
  __syncthreads();

  int d = dh*256 + tid;
  const float* hb = h1 + (size_t)b*NLQ*ND;
  float acc[25];
  #pragma unroll
  for(int r=0;r<25;r++) acc[r]=0.f;
  for(int jj=0; jj<NLQ; jj++){
    float hv = hb[(size_t)jj*ND + d];
    #pragma unroll
    for(int r=0;r<25;r++) acc[r] += att[r][jj]*hv;
  }
  #pragma unroll
  for(int r=0;r<25;r++){
    int l = r/5, k = r - l*5;
    y[(size_t)l*MN + ((size_t)b*8+k)*ND + d] = acc[r];
  }
  #pragma unroll
  for(int l=0;l<5;l++)
    #pragma unroll
    for(int k=5;k<8;k++)
      y[(size_t)l*MN + ((size_t)b*8+k)*ND + d] = 0.f;
}

__global__ __launch_bounds__(256) void k_g(const float* __restrict__ hp,
    const int* __restrict__ asp, float* __restrict__ g){
  int b = blockIdx.x, d = threadIdx.x;
  int nk = asp[b];
  float gx=0.f, gy=0.f;
  for(int l=0;l<5;l++){
    for(int k=0;k<nk;k++){
      const float* r = hp + (size_t)l*MN + (size_t)(b*8+k)*ND;
      gx += fmaxf(r[d], 0.f);
      gy += fmaxf(r[d+256], 0.f);
    }
  }
  g[b*ND + d]       = 0.2f*gx;
  g[b*ND + 256 + d] = 0.2f*gy;
}

__global__ __launch_bounds__(256) void k_dot(const float* __restrict__ x,
    const float* __restrict__ g, float* __restrict__ s){
  int row  = blockIdx.x*4 + (threadIdx.x>>6);
  int b    = row >> 8;
  int lane = threadIdx.x & 63;
  const float4* xr = (const float4*)(x + (size_t)row*ND);
  const float4* gr = (const float4*)(g + (size_t)b*ND);
  float4 x0=xr[lane], x1=xr[lane+64], g0=gr[lane], g1=gr[lane+64];
  float d = x0.x*g0.x + x0.y*g0.y + x0.z*g0.z + x0.w*g0.w
          + x1.x*g1.x + x1.y*g1.y + x1.z*g1.z + x1.w*g1.w;
  d = wave_sum(d);
  if(lane==0) s[row] = d;
}

__global__ __launch_bounds__(256) void k_out(const float* __restrict__ x,
    const float* __restrict__ s, float* __restrict__ out){
  int b  = blockIdx.x >> 2;
  int ch = blockIdx.x & 3;
  int tid = threadIdx.x, lane = tid&63, w = tid>>6;
  __shared__ float red[4];
  __shared__ float alpha[NLQ];
  __shared__ float part[128];
  float sv = s[b*NLQ + tid];
  float m = wave_max(sv);
  if(lane==0) red[w] = m;
  __syncthreads();
  m = fmaxf(fmaxf(red[0],red[1]), fmaxf(red[2],red[3]));
  float p = __expf(sv - m);
  float su = wave_sum(p);
  __syncthreads();
  if(lane==0) red[w] = su;
  __syncthreads();
  su = red[0]+red[1]+red[2]+red[3];
  alpha[tid] = p/su;
  __syncthreads();
  int d = ch*128 + (tid & 127);
  int half = tid >> 7;
  const float* xb = x + (size_t)b*NLQ*ND;
  float acc = 0.f;
  for(int mm = half*128; mm < half*128 + 128; mm++)
    acc += alpha[mm] * xb[(size_t)mm*ND + d];
  if(half) part[tid & 127] = acc;
  __syncthreads();
  if(!half) out[(size_t)b*ND + d] = acc + part[tid & 127];
}

extern "C" void kernel_launch(void* const* d_in, const int* in_sizes, int n_in,
                              void* d_out, int out_size, void* d_ws, size_t ws_size,
                              hipStream_t stream){
  const float* x    = (const float*)d_in[0];
  const float* Wst  = (const float*)d_in[1];
  const float* ast  = (const float*)d_in[2];
  const int*   adj  = (const int*)d_in[3];
  const int*   left = (const int*)d_in[4];
  const int*   asp  = (const int*)d_in[5];
  const int*   tl   = (const int*)d_in[6];
  float* out = (float*)d_out;
  float* ws  = (float*)d_ws;

  const size_t SZ = (size_t)NB*NLQ*ND;
  float* bufA = ws;              // xp -> h1
  float* bufB = ws + SZ;         // h0T; later Hasp/ybuf/hp/R
  float* ws2  = ws + 2*SZ;
  float* tpart= ws2;                    // 65536
  float* T    = ws2 + 65536;            // 163840
  float* g    = T + 163840;             // 65536
  float* scal = g + 65536;              // 16
  float* v    = scal + 16;              // 2560
  float* sbuf = v + 2560;               // 32768
  unsigned long long* adjT = (unsigned long long*)(sbuf + 32768);  // 131072 u64

  float* Hasp = bufB;
  float* ybuf = Hasp + (size_t)5*MN;
  float* hp   = ybuf + (size_t)5*MN;
  float* R    = hp   + (size_t)5*MN;

  k_scal<<<NLAYERS, 256, 0, stream>>>(ast, scal);
  k_wa2<<<5*128, 256, 0, stream>>>(Wst, ast, v);
  k_adjp<<<NB*4, 256, 0, stream>>>(adj, adjT);
  k_posw<<<NB*NLQ*ND/1024, 256, 0, stream>>>(x, bufA, left, asp, tl);

  // layer 0: h0T = (xp @ W0)^T per batch; t partials; MFMA attention -> h1
  k_gemm_t<<<(NB*NLQ/128)*(ND/128), 256, 0, stream>>>(bufA, Wst, bufB);
  k_tT<<<NB*2, 256, 0, stream>>>(bufB, ast + ND, tpart);
  k_attn0<<<NB*8, 256, 0, stream>>>(bufB, adjT, tpart, scal, left, asp, tl, bufA);

  // layers 1..5 on aspect rows only
  k_tv<<<NB*NLQ/4, 256, 0, stream>>>(bufA, v, T);
  k_rows<<<NB, 256, 0, stream>>>(bufA, left, asp, R);
  k_gemm_b<<<5*32, 256, 0, stream>>>(R, 0L, Wst, Hasp);
  k_att5<<<NB*2, 256, 0, stream>>>(bufA, Hasp, T, adj, scal, left, asp, ybuf);
  k_gemm_b<<<5*32, 256, 0, stream>>>(ybuf, (long)MN, Wst, hp);
  k_g<<<NB, 256, 0, stream>>>(hp, asp, g);

  // final attention over original x
  k_dot<<<NB*NLQ/4, 256, 0, stream>>>(x, g, sbuf);
  k_out<<<NB*4, 256, 0, stream>>>(x, sbuf, out);
}